// Round 14
// baseline (509.172 us; speedup 1.0000x reference)
//
#include <hip/hip_runtime.h>
#include <math.h>

#define BATCH 4
#define SEQ   1024
#define DM    256
#define NH    8
#define DHD   32
#define NL    4
#define FF1   1024
#define OUTD  20

typedef _Float16 f16;
typedef _Float16 f16x8 __attribute__((ext_vector_type(8)));
typedef _Float16 f16x4 __attribute__((ext_vector_type(4)));
typedef float    f32x4 __attribute__((ext_vector_type(4)));

// ---------------------------------------------------------------------------
// padding_mask canonicalization (int32 vs u8 upload) -> u8[4096]
// ---------------------------------------------------------------------------
__global__ void pad_kernel(const void* __restrict__ praw, unsigned char* __restrict__ pad)
{
    __shared__ int isInt;
    const int tid = threadIdx.x;
    const unsigned char* pb = (const unsigned char*)praw;
    if (tid == 0) isInt = 1;
    __syncthreads();
    unsigned char any = 0;
    for (int p = tid; p < BATCH * SEQ; p += 1024)
        if ((p & 3) && pb[p]) any = 1;
    if (any) isInt = 0;
    __syncthreads();
    const int ii = isInt;
    for (int e = tid; e < BATCH * SEQ; e += 1024)
        pad[e] = ii ? (unsigned char)(((const int*)praw)[e] != 0)
                    : (unsigned char)(pb[e] != 0);
}

// ---------------------------------------------------------------------------
// bit-packed blocked mask
// ---------------------------------------------------------------------------
__global__ __launch_bounds__(256) void mask_kernel(const float* __restrict__ P,
                                                   const unsigned char* __restrict__ pad,
                                                   unsigned int* __restrict__ mbits)
{
    const int bi = blockIdx.x;
    const int b = bi >> 10, i = bi & 1023;
    const float* Pb = P + (size_t)b * SEQ * 5;
    const float z1 = Pb[i * 5 + 0], r1 = Pb[i * 5 + 1];
    const float p1 = Pb[i * 5 + 2], e1 = Pb[i * 5 + 3];
    const unsigned char pad_i = pad[bi];
    unsigned int* mrow = mbits + (size_t)bi * (SEQ / 32);
    const float PI_F  = 3.14159265358979323846f;
    const float TPI_F = 6.28318530717958647692f;
    const int lane = threadIdx.x & 63;
    const int wv = threadIdx.x >> 6;
    for (int t = 0; t < 4; ++t) {
        const int j = threadIdx.x + t * 256;
        const unsigned char pad_j = pad[b * SEQ + j];
        bool blocked;
        if (pad_i || pad_j || i == j) {
            blocked = (pad_j != 0);
        } else {
            const float z2 = Pb[j * 5 + 0], r2 = Pb[j * 5 + 1];
            const float p2 = Pb[j * 5 + 2], e2 = Pb[j * 5 + 3];
            const float rdiff = r2 - r1;
            const float z0 = (rdiff != 0.f) ? fabsf(z1 - r1 * (z2 - z1) / rdiff) : 1e6f;
            float pdiff = fabsf(p2 - p1);
            if (pdiff > PI_F) pdiff = TPI_F - pdiff;
            const float ratio = pdiff / (fabsf(rdiff) + 1e-8f);
            const float ang = sqrtf((e2 - e1) * (e2 - e1) + pdiff * pdiff);
            blocked = (z0 > 197.4f) && (ratio > 0.001825f) && (ang > 1.797f);
        }
        const unsigned long long bal = __ballot(blocked);
        if (lane == 0) {
            const int w0 = wv * 2 + t * 8;
            mrow[w0 + 0] = (unsigned int)bal;
            mrow[w0 + 1] = (unsigned int)(bal >> 32);
        }
    }
}

// ---------------------------------------------------------------------------
// embed: x f32 + xh f16
// ---------------------------------------------------------------------------
__global__ __launch_bounds__(256) void embed_kernel(const float* __restrict__ in,
                                                    const float* __restrict__ w_in,
                                                    const float* __restrict__ b_in,
                                                    float* __restrict__ x,
                                                    f16* __restrict__ xh)
{
    const int row = blockIdx.x;
    const int d = threadIdx.x;
    const float i0 = in[row * 3 + 0], i1 = in[row * 3 + 1], i2 = in[row * 3 + 2];
    const float v = b_in[d] + i0 * w_in[d * 3 + 0] + i1 * w_in[d * 3 + 1] + i2 * w_in[d * 3 + 2];
    x[(size_t)row * DM + d] = v;
    xh[(size_t)row * DM + d] = (f16)v;
}

// ---------------------------------------------------------------------------
// merged f32 -> f16 cast of all 4 weight tensors (single dispatch)
// segment sizes are multiples of 8 so thread chunks never straddle segments
// ---------------------------------------------------------------------------
__global__ __launch_bounds__(256) void castw4_kernel(const float* __restrict__ s0, f16* __restrict__ d0, int n0,
                                                     const float* __restrict__ s1, f16* __restrict__ d1, int n1,
                                                     const float* __restrict__ s2, f16* __restrict__ d2, int n2,
                                                     const float* __restrict__ s3, f16* __restrict__ d3, int n3)
{
    const int i = (blockIdx.x * 256 + threadIdx.x) * 8;
    const float* s; f16* d; int base;
    if      (i < n0)                { s = s0; d = d0; base = 0; }
    else if (i < n0 + n1)           { s = s1; d = d1; base = n0; }
    else if (i < n0 + n1 + n2)      { s = s2; d = d2; base = n0 + n1; }
    else if (i < n0 + n1 + n2 + n3) { s = s3; d = d3; base = n0 + n1 + n2; }
    else return;
    const int j = i - base;
    f16x8 o;
    #pragma unroll
    for (int k = 0; k < 8; ++k) o[k] = (f16)s[j + k];
    *(f16x8*)&d[j] = o;
}

// ---------------------------------------------------------------------------
// MFMA GEMM v2: BT x BT tile, 4 waves (2x2), BK=64 (2 k-substeps of 32).
// mode 0: f32 out; mode 1: f16 out; mode 2: f16 head-split (qkv, N=768):
//   col -> sec(q/k/v), head h, dim d; writes Qh/Kh/Vh[(b*8+h)][s][d].
// Frag convention: A/B row=lane&15, k=(lane>>4)*8+e;
// D row=(lane>>4)*4+reg (M), col=lane&15 (N).
// ---------------------------------------------------------------------------
template<int BT>
__global__ __launch_bounds__(256) void mgemm_kernel(const f16* __restrict__ A,
                                                    const f16* __restrict__ W,
                                                    const float* __restrict__ bias,
                                                    void* __restrict__ C,
                                                    int M, int N, int K, int relu, int mode,
                                                    f16* __restrict__ Qh,
                                                    f16* __restrict__ Kh,
                                                    f16* __restrict__ Vh)
{
    constexpr int WT = BT / 2;
    constexpr int MF = WT / 16;
    constexpr int LDT = 72;                 // 64 cols + 8 pad
    __shared__ f16 Al[BT * LDT];
    __shared__ f16 Wl[BT * LDT];
    const int tid = threadIdx.x;
    const int lane = tid & 63, g = lane >> 4, fr = lane & 15;
    const int wv = tid >> 6, wm = wv >> 1, wn = wv & 1;
    const int m0 = blockIdx.y * BT, n0 = blockIdx.x * BT;

    f32x4 acc[MF][MF] = {};
    for (int k0 = 0; k0 < K; k0 += 64) {
        __syncthreads();
        #pragma unroll
        for (int u = 0; u < BT / 32; ++u) {
            const int idx = tid + u * 256;
            const int row = idx >> 3, col = (idx & 7) * 8;
            *(f16x8*)&Al[row * LDT + col] = *(const f16x8*)&A[(size_t)(m0 + row) * K + k0 + col];
            *(f16x8*)&Wl[row * LDT + col] = *(const f16x8*)&W[(size_t)(n0 + row) * K + k0 + col];
        }
        __syncthreads();
        #pragma unroll
        for (int ks = 0; ks < 2; ++ks) {
            f16x8 af[MF], wf[MF];
            #pragma unroll
            for (int m = 0; m < MF; ++m)
                af[m] = *(const f16x8*)&Al[(wm * WT + m * 16 + fr) * LDT + ks * 32 + g * 8];
            #pragma unroll
            for (int n = 0; n < MF; ++n)
                wf[n] = *(const f16x8*)&Wl[(wn * WT + n * 16 + fr) * LDT + ks * 32 + g * 8];
            #pragma unroll
            for (int m = 0; m < MF; ++m)
                #pragma unroll
                for (int n = 0; n < MF; ++n)
                    acc[m][n] = __builtin_amdgcn_mfma_f32_16x16x32_f16(af[m], wf[n], acc[m][n], 0, 0, 0);
        }
    }
    #pragma unroll
    for (int m = 0; m < MF; ++m)
        #pragma unroll
        for (int n = 0; n < MF; ++n) {
            const int col = n0 + wn * WT + n * 16 + fr;
            const float bs = bias[col];
            #pragma unroll
            for (int r = 0; r < 4; ++r) {
                const int row = m0 + wm * WT + m * 16 + g * 4 + r;
                float v = acc[m][n][r] + bs;
                if (relu) v = fmaxf(v, 0.f);
                if (mode == 0) {
                    ((float*)C)[(size_t)row * N + col] = v;
                } else if (mode == 1) {
                    ((f16*)C)[(size_t)row * N + col] = (f16)v;
                } else {
                    const int b = row >> 10, s = row & 1023;
                    const int sec = col >> 8, c = col & 255;
                    const int h = c >> 5, d = c & 31;
                    const size_t dst = (((size_t)(b * NH + h) * SEQ) + s) * DHD + d;
                    f16* base = (sec == 0) ? Qh : (sec == 1) ? Kh : Vh;
                    base[dst] = (f16)v;
                }
            }
        }
}

// ---------------------------------------------------------------------------
// MFMA flash attention (f16). Block: 4 waves x 16 queries = 64 q; grid (16,32).
// Swapped QK^T: S^T = mfma(A=K, B=Q) -> lane owns q=lane&15, k=f*16+g*4+r.
// P staged per-wave in LDS with stride 72 (64 keys + 8 pad).
// ---------------------------------------------------------------------------
__global__ __launch_bounds__(256) void attn3_kernel(const f16* __restrict__ Qh,
                                                    const f16* __restrict__ Kh,
                                                    const f16* __restrict__ Vh,
                                                    const unsigned int* __restrict__ mbits,
                                                    f16* __restrict__ out)
{
    __shared__ f16 Kl[64 * 40];
    __shared__ f16 Vt[32 * 72];      // V^T [d][k], stride 72
    __shared__ f16 Ql[64 * 40];
    __shared__ f16 Pl[4][16 * 72];   // per-wave P: 16 q-rows x 64 keys + pad
    __shared__ unsigned int Ml[64][2];
    const int bh = blockIdx.y, b = bh >> 3, h = bh & 7;
    const int q0 = blockIdx.x * 64;
    const int tid = threadIdx.x, wv = tid >> 6, lane = tid & 63;
    const int g = lane >> 4, fr = lane & 15;
    const size_t kvbase = (size_t)bh * SEQ * DHD;

    {   // stage Q (64x32)
        const int row = tid >> 2, col = (tid & 3) * 8;
        *(f16x8*)&Ql[row * 40 + col] = *(const f16x8*)&Qh[kvbase + (size_t)(q0 + row) * DHD + col];
    }
    const int mrowbase = b * SEQ + q0;
    const float scale = 0.17677669529663687f;
    float mrun = -3.0e38f, lrun = 0.f;
    f32x4 o0 = {0.f, 0.f, 0.f, 0.f}, o1 = {0.f, 0.f, 0.f, 0.f};

    for (int t = 0; t < 16; ++t) {
        __syncthreads();
        {   // stage K tile (64x32)
            const int row = tid >> 2, col = (tid & 3) * 8;
            *(f16x8*)&Kl[row * 40 + col] = *(const f16x8*)&Kh[kvbase + (size_t)(t * 64 + row) * DHD + col];
        }
        {   // stage V^T: thread reads V[k][d0..d0+7], writes transposed
            const int k = tid & 63, d0 = (tid >> 6) * 8;
            const f16x8 v = *(const f16x8*)&Vh[kvbase + (size_t)(t * 64 + k) * DHD + d0];
            #pragma unroll
            for (int j = 0; j < 8; ++j) Vt[(d0 + j) * 72 + k] = v[j];
        }
        if (tid < 128) {   // stage mask words (2 per query)
            const int i = tid >> 1, w = tid & 1;
            Ml[i][w] = mbits[(size_t)(mrowbase + i) * (SEQ / 32) + t * 2 + w];
        }
        __syncthreads();

        const f16x8 bq = *(const f16x8*)&Ql[(wv * 16 + fr) * 40 + g * 8];
        f32x4 s[4];
        #pragma unroll
        for (int f = 0; f < 4; ++f) {
            const f16x8 ak = *(const f16x8*)&Kl[(f * 16 + fr) * 40 + g * 8];
            const f32x4 z = {0.f, 0.f, 0.f, 0.f};
            s[f] = __builtin_amdgcn_mfma_f32_16x16x32_f16(ak, bq, z, 0, 0, 0);
        }
        const unsigned long long mb =
            ((unsigned long long)Ml[wv * 16 + fr][1] << 32) | (unsigned long long)Ml[wv * 16 + fr][0];
        float tm = -3.0e38f;
        #pragma unroll
        for (int f = 0; f < 4; ++f)
            #pragma unroll
            for (int r = 0; r < 4; ++r) {
                const int kk = f * 16 + g * 4 + r;
                const float v = ((mb >> kk) & 1ULL) ? -1e9f : s[f][r] * scale;
                s[f][r] = v;
                tm = fmaxf(tm, v);
            }
        tm = fmaxf(tm, __shfl_xor(tm, 16, 64));
        tm = fmaxf(tm, __shfl_xor(tm, 32, 64));
        const float mnew = fmaxf(mrun, tm);
        const float resc = __expf(mrun - mnew);
        mrun = mnew;
        lrun *= resc;
        float ps = 0.f;
        #pragma unroll
        for (int f = 0; f < 4; ++f)
            #pragma unroll
            for (int r = 0; r < 4; ++r) {
                const float p = __expf(s[f][r] - mnew);
                s[f][r] = p;
                ps += p;
            }
        ps += __shfl_xor(ps, 16, 64);
        ps += __shfl_xor(ps, 32, 64);
        lrun += ps;
        #pragma unroll
        for (int r = 0; r < 4; ++r) {
            const float rs = __shfl(resc, g * 4 + r, 64);
            o0[r] *= rs;
            o1[r] *= rs;
        }
        // P (this lane: q=fr, k=f*16+g*4+0..3) -> f16 -> wave-private LDS
        #pragma unroll
        for (int f = 0; f < 4; ++f) {
            f16x4 pw = { (f16)s[f][0], (f16)s[f][1], (f16)s[f][2], (f16)s[f][3] };
            *(f16x4*)&Pl[wv][fr * 72 + f * 16 + g * 4] = pw;
        }
        #pragma unroll
        for (int kh = 0; kh < 2; ++kh) {
            const f16x8 pa = *(const f16x8*)&Pl[wv][fr * 72 + kh * 32 + g * 8];
            const f16x8 v0 = *(const f16x8*)&Vt[fr * 72 + kh * 32 + g * 8];
            const f16x8 v1 = *(const f16x8*)&Vt[(16 + fr) * 72 + kh * 32 + g * 8];
            o0 = __builtin_amdgcn_mfma_f32_16x16x32_f16(pa, v0, o0, 0, 0, 0);
            o1 = __builtin_amdgcn_mfma_f32_16x16x32_f16(pa, v1, o1, 0, 0, 0);
        }
    }
    #pragma unroll
    for (int r = 0; r < 4; ++r) {
        const float inv = 1.f / __shfl(lrun, g * 4 + r, 64);
        const int qg = q0 + wv * 16 + g * 4 + r;
        f16* orow = out + ((size_t)(b * SEQ + qg)) * DM + h * DHD;
        orow[fr]      = (f16)(o0[r] * inv);
        orow[16 + fr] = (f16)(o1[r] * inv);
    }
}

// ---------------------------------------------------------------------------
// x = LayerNorm(x + t)*g + b ; also f16 mirror xh
// ---------------------------------------------------------------------------
__global__ __launch_bounds__(256) void add_ln_kernel(float* __restrict__ x,
                                                     f16* __restrict__ xh,
                                                     const float* __restrict__ t,
                                                     const float* __restrict__ g,
                                                     const float* __restrict__ b)
{
    __shared__ float red[256];
    const int row = blockIdx.x, tid = threadIdx.x;
    const size_t idx = (size_t)row * DM + tid;
    const float v = x[idx] + t[idx];
    red[tid] = v;
    __syncthreads();
    for (int s = 128; s; s >>= 1) { if (tid < s) red[tid] += red[tid + s]; __syncthreads(); }
    const float mean = red[0] * (1.f / DM);
    __syncthreads();
    const float d = v - mean;
    red[tid] = d * d;
    __syncthreads();
    for (int s = 128; s; s >>= 1) { if (tid < s) red[tid] += red[tid + s]; __syncthreads(); }
    const float var = red[0] * (1.f / DM);
    const float rs = rsqrtf(var + 1e-5f);
    const float o = d * rs * g[tid] + b[tid];
    x[idx] = o;
    xh[idx] = (f16)o;
}

// ---------------------------------------------------------------------------
// decoder (f32)
// ---------------------------------------------------------------------------
__global__ __launch_bounds__(256) void dec_kernel(const float* __restrict__ x,
                                                  const float* __restrict__ w,
                                                  const float* __restrict__ bias,
                                                  float* __restrict__ out)
{
    const int idx = blockIdx.x * 256 + threadIdx.x;
    if (idx >= BATCH * SEQ * OUTD) return;
    const int row = idx / OUTD, o = idx % OUTD;
    const float* xr = x + (size_t)row * DM;
    const float* wr = w + o * DM;
    float s = bias[o];
    for (int d = 0; d < DM; ++d) s += xr[d] * wr[d];
    out[idx] = s;
}

// ---------------------------------------------------------------------------
extern "C" void kernel_launch(void* const* d_in, const int* in_sizes, int n_in,
                              void* d_out, int out_size, void* d_ws, size_t ws_size,
                              hipStream_t stream)
{
    (void)in_sizes; (void)n_in; (void)out_size; (void)ws_size;
    const float* in_coord = (const float*)d_in[0];
    const float* in_maskf = (const float*)d_in[1];
    const void*  praw     = d_in[2];
    const float* w_in  = (const float*)d_in[3];
    const float* b_in  = (const float*)d_in[4];
    const float* w_qkv = (const float*)d_in[5];
    const float* b_qkv = (const float*)d_in[6];
    const float* w_o   = (const float*)d_in[7];
    const float* b_o   = (const float*)d_in[8];
    const float* w_ff1 = (const float*)d_in[9];
    const float* b_ff1 = (const float*)d_in[10];
    const float* w_ff2 = (const float*)d_in[11];
    const float* b_ff2 = (const float*)d_in[12];
    const float* ln1_g = (const float*)d_in[13];
    const float* ln1_b = (const float*)d_in[14];
    const float* ln2_g = (const float*)d_in[15];
    const float* ln2_b = (const float*)d_in[16];
    const float* w_dec = (const float*)d_in[17];
    const float* b_dec = (const float*)d_in[18];

    const int ROWS = BATCH * SEQ;                 // 4096
    float* x   = (float*)d_ws;                    // 1M f32
    float* tmp = x + 1048576;                     // 1M f32
    f16* us = (f16*)(tmp + 1048576);
    f16* xh    = us;  us += 1048576;
    f16* Qh    = us;  us += 1048576;
    f16* Kh    = us;  us += 1048576;
    f16* Vh    = us;  us += 1048576;
    f16* attno = us;  us += 1048576;
    f16* hb    = us;  us += 4194304;
    f16* wqb   = us;  us += 786432;
    f16* wob   = us;  us += 262144;
    f16* w1b   = us;  us += 1048576;
    f16* w2b   = us;  us += 1048576;
    unsigned int*  mbits  = (unsigned int*)us;    // 131072 u32
    unsigned char* padb   = (unsigned char*)(mbits + 131072);

    hipLaunchKernelGGL(pad_kernel, dim3(1), dim3(1024), 0, stream, praw, padb);
    hipLaunchKernelGGL(mask_kernel, dim3(BATCH * SEQ), dim3(256), 0, stream,
                       in_maskf, padb, mbits);
    hipLaunchKernelGGL(embed_kernel, dim3(ROWS), dim3(256), 0, stream,
                       in_coord, w_in, b_in, x, xh);
    // all weight casts in ONE dispatch: 3145728 elems / 8 per thread / 256 = 1536 blocks
    hipLaunchKernelGGL(castw4_kernel, dim3(1536), dim3(256), 0, stream,
                       w_qkv, wqb, 786432,
                       w_o,   wob, 262144,
                       w_ff1, w1b, 1048576,
                       w_ff2, w2b, 1048576);

    for (int l = 0; l < NL; ++l) {
        // qkv GEMM, epilogue writes head-split Qh/Kh/Vh directly (mode 2)
        hipLaunchKernelGGL((mgemm_kernel<64>), dim3(768 / 64, ROWS / 64), dim3(256), 0, stream,
                           xh, wqb + (size_t)l * 196608, b_qkv + l * 768, (void*)0,
                           ROWS, 768, 256, 0, 2, Qh, Kh, Vh);
        hipLaunchKernelGGL(attn3_kernel, dim3(SEQ / 64, BATCH * NH), dim3(256), 0, stream,
                           Qh, Kh, Vh, mbits, attno);
        hipLaunchKernelGGL((mgemm_kernel<64>), dim3(256 / 64, ROWS / 64), dim3(256), 0, stream,
                           attno, wob + (size_t)l * 65536, b_o + l * 256, (void*)tmp,
                           ROWS, 256, 256, 0, 0, (f16*)0, (f16*)0, (f16*)0);
        hipLaunchKernelGGL(add_ln_kernel, dim3(ROWS), dim3(256), 0, stream,
                           x, xh, tmp, ln1_g + l * DM, ln1_b + l * DM);
        hipLaunchKernelGGL((mgemm_kernel<64>), dim3(1024 / 64, ROWS / 64), dim3(256), 0, stream,
                           xh, w1b + (size_t)l * 262144, b_ff1 + l * 1024, (void*)hb,
                           ROWS, 1024, 256, 1, 1, (f16*)0, (f16*)0, (f16*)0);
        hipLaunchKernelGGL((mgemm_kernel<64>), dim3(256 / 64, ROWS / 64), dim3(256), 0, stream,
                           hb, w2b + (size_t)l * 262144, b_ff2 + l * 256, (void*)tmp,
                           ROWS, 256, 1024, 0, 0, (f16*)0, (f16*)0, (f16*)0);
        hipLaunchKernelGGL(add_ln_kernel, dim3(ROWS), dim3(256), 0, stream,
                           x, xh, tmp, ln2_g + l * DM, ln2_b + l * DM);
    }

    hipLaunchKernelGGL(dec_kernel, dim3((ROWS * OUTD + 255) / 256), dim3(256), 0, stream,
                       x, w_dec, b_dec, (float*)d_out);
}

// Round 17
// 461.923 us; speedup vs baseline: 1.1023x; 1.1023x over previous
//
#include <hip/hip_runtime.h>
#include <math.h>

#define BATCH 4
#define SEQ   1024
#define DM    256
#define NH    8
#define DHD   32
#define NL    4
#define FF1   1024
#define OUTD  20

typedef _Float16 f16;
typedef _Float16 f16x8 __attribute__((ext_vector_type(8)));
typedef _Float16 f16x4 __attribute__((ext_vector_type(4)));
typedef float    f32x4 __attribute__((ext_vector_type(4)));

// ---------------------------------------------------------------------------
// padding_mask canonicalization (int32 vs u8 upload) -> u8[4096]
// ---------------------------------------------------------------------------
__global__ void pad_kernel(const void* __restrict__ praw, unsigned char* __restrict__ pad)
{
    __shared__ int isInt;
    const int tid = threadIdx.x;
    const unsigned char* pb = (const unsigned char*)praw;
    if (tid == 0) isInt = 1;
    __syncthreads();
    unsigned char any = 0;
    for (int p = tid; p < BATCH * SEQ; p += 1024)
        if ((p & 3) && pb[p]) any = 1;
    if (any) isInt = 0;
    __syncthreads();
    const int ii = isInt;
    for (int e = tid; e < BATCH * SEQ; e += 1024)
        pad[e] = ii ? (unsigned char)(((const int*)praw)[e] != 0)
                    : (unsigned char)(pb[e] != 0);
}

// ---------------------------------------------------------------------------
// bit-packed blocked mask
// ---------------------------------------------------------------------------
__global__ __launch_bounds__(256) void mask_kernel(const float* __restrict__ P,
                                                   const unsigned char* __restrict__ pad,
                                                   unsigned int* __restrict__ mbits)
{
    const int bi = blockIdx.x;
    const int b = bi >> 10, i = bi & 1023;
    const float* Pb = P + (size_t)b * SEQ * 5;
    const float z1 = Pb[i * 5 + 0], r1 = Pb[i * 5 + 1];
    const float p1 = Pb[i * 5 + 2], e1 = Pb[i * 5 + 3];
    const unsigned char pad_i = pad[bi];
    unsigned int* mrow = mbits + (size_t)bi * (SEQ / 32);
    const float PI_F  = 3.14159265358979323846f;
    const float TPI_F = 6.28318530717958647692f;
    const int lane = threadIdx.x & 63;
    const int wv = threadIdx.x >> 6;
    for (int t = 0; t < 4; ++t) {
        const int j = threadIdx.x + t * 256;
        const unsigned char pad_j = pad[b * SEQ + j];
        bool blocked;
        if (pad_i || pad_j || i == j) {
            blocked = (pad_j != 0);
        } else {
            const float z2 = Pb[j * 5 + 0], r2 = Pb[j * 5 + 1];
            const float p2 = Pb[j * 5 + 2], e2 = Pb[j * 5 + 3];
            const float rdiff = r2 - r1;
            const float z0 = (rdiff != 0.f) ? fabsf(z1 - r1 * (z2 - z1) / rdiff) : 1e6f;
            float pdiff = fabsf(p2 - p1);
            if (pdiff > PI_F) pdiff = TPI_F - pdiff;
            const float ratio = pdiff / (fabsf(rdiff) + 1e-8f);
            const float ang = sqrtf((e2 - e1) * (e2 - e1) + pdiff * pdiff);
            blocked = (z0 > 197.4f) && (ratio > 0.001825f) && (ang > 1.797f);
        }
        const unsigned long long bal = __ballot(blocked);
        if (lane == 0) {
            const int w0 = wv * 2 + t * 8;
            mrow[w0 + 0] = (unsigned int)bal;
            mrow[w0 + 1] = (unsigned int)(bal >> 32);
        }
    }
}

// ---------------------------------------------------------------------------
// embed: x f32 + xh f16
// ---------------------------------------------------------------------------
__global__ __launch_bounds__(256) void embed_kernel(const float* __restrict__ in,
                                                    const float* __restrict__ w_in,
                                                    const float* __restrict__ b_in,
                                                    float* __restrict__ x,
                                                    f16* __restrict__ xh)
{
    const int row = blockIdx.x;
    const int d = threadIdx.x;
    const float i0 = in[row * 3 + 0], i1 = in[row * 3 + 1], i2 = in[row * 3 + 2];
    const float v = b_in[d] + i0 * w_in[d * 3 + 0] + i1 * w_in[d * 3 + 1] + i2 * w_in[d * 3 + 2];
    x[(size_t)row * DM + d] = v;
    xh[(size_t)row * DM + d] = (f16)v;
}

// ---------------------------------------------------------------------------
// merged f32 -> f16 cast of all 4 weight tensors (single dispatch)
// ---------------------------------------------------------------------------
__global__ __launch_bounds__(256) void castw4_kernel(const float* __restrict__ s0, f16* __restrict__ d0, int n0,
                                                     const float* __restrict__ s1, f16* __restrict__ d1, int n1,
                                                     const float* __restrict__ s2, f16* __restrict__ d2, int n2,
                                                     const float* __restrict__ s3, f16* __restrict__ d3, int n3)
{
    const int i = (blockIdx.x * 256 + threadIdx.x) * 8;
    const float* s; f16* d; int base;
    if      (i < n0)                { s = s0; d = d0; base = 0; }
    else if (i < n0 + n1)           { s = s1; d = d1; base = n0; }
    else if (i < n0 + n1 + n2)      { s = s2; d = d2; base = n0 + n1; }
    else if (i < n0 + n1 + n2 + n3) { s = s3; d = d3; base = n0 + n1 + n2; }
    else return;
    const int j = i - base;
    f16x8 o;
    #pragma unroll
    for (int k = 0; k < 8; ++k) o[k] = (f16)s[j + k];
    *(f16x8*)&d[j] = o;
}

// ---------------------------------------------------------------------------
// MFMA GEMM (R12-proven): BT x BT tile, 4 waves (2x2), BK=32.
// Frag convention: A/B row=lane&15, k=(lane>>4)*8+e;
// D row=(lane>>4)*4+reg (M), col=lane&15 (N).
// ---------------------------------------------------------------------------
template<int BT>
__global__ __launch_bounds__(256) void mgemm_kernel(const f16* __restrict__ A,
                                                    const f16* __restrict__ W,
                                                    const float* __restrict__ bias,
                                                    void* __restrict__ C,
                                                    int M, int N, int K, int relu, int of16)
{
    constexpr int WT = BT / 2;
    constexpr int MF = WT / 16;
    constexpr int LDT = 40;                 // 32 cols + 8 pad
    __shared__ f16 Al[BT * LDT];
    __shared__ f16 Wl[BT * LDT];
    const int tid = threadIdx.x;
    const int lane = tid & 63, g = lane >> 4, fr = lane & 15;
    const int wv = tid >> 6, wm = wv >> 1, wn = wv & 1;
    const int m0 = blockIdx.y * BT, n0 = blockIdx.x * BT;

    f32x4 acc[MF][MF] = {};
    for (int k0 = 0; k0 < K; k0 += 32) {
        __syncthreads();
        #pragma unroll
        for (int u = 0; u < BT / 64; ++u) {
            const int row = (tid >> 2) + u * 64, col = (tid & 3) * 8;
            *(f16x8*)&Al[row * LDT + col] = *(const f16x8*)&A[(size_t)(m0 + row) * K + k0 + col];
            *(f16x8*)&Wl[row * LDT + col] = *(const f16x8*)&W[(size_t)(n0 + row) * K + k0 + col];
        }
        __syncthreads();
        f16x8 af[MF], wf[MF];
        #pragma unroll
        for (int m = 0; m < MF; ++m)
            af[m] = *(const f16x8*)&Al[(wm * WT + m * 16 + fr) * LDT + g * 8];
        #pragma unroll
        for (int n = 0; n < MF; ++n)
            wf[n] = *(const f16x8*)&Wl[(wn * WT + n * 16 + fr) * LDT + g * 8];
        #pragma unroll
        for (int m = 0; m < MF; ++m)
            #pragma unroll
            for (int n = 0; n < MF; ++n)
                acc[m][n] = __builtin_amdgcn_mfma_f32_16x16x32_f16(af[m], wf[n], acc[m][n], 0, 0, 0);
    }
    #pragma unroll
    for (int m = 0; m < MF; ++m)
        #pragma unroll
        for (int n = 0; n < MF; ++n) {
            const int col = n0 + wn * WT + n * 16 + fr;
            const float bs = bias[col];
            #pragma unroll
            for (int r = 0; r < 4; ++r) {
                const int row = m0 + wm * WT + m * 16 + g * 4 + r;
                float v = acc[m][n][r] + bs;
                if (relu) v = fmaxf(v, 0.f);
                if (of16) ((f16*)C)[(size_t)row * N + col] = (f16)v;
                else      ((float*)C)[(size_t)row * N + col] = v;
            }
        }
}

// ---------------------------------------------------------------------------
// split heads (f16): qkv[B*S][768] -> Qh/Kh/Vh[(b*8+h)][s][32]
// ---------------------------------------------------------------------------
__global__ __launch_bounds__(256) void split_heads_kernel(const f16* __restrict__ qkv,
                                                          f16* __restrict__ Qh,
                                                          f16* __restrict__ Kh,
                                                          f16* __restrict__ Vh)
{
    const int row = blockIdx.x;
    const int b = row >> 10, s = row & 1023;
    const int c = threadIdx.x;
    const int h = c >> 5, d = c & 31;
    const size_t dst = (((size_t)(b * NH + h) * SEQ) + s) * DHD + d;
    const f16* src = qkv + (size_t)row * 768;
    Qh[dst] = src[c];
    Kh[dst] = src[256 + c];
    Vh[dst] = src[512 + c];
}

// ---------------------------------------------------------------------------
// MFMA flash attention (f16), R12-proven. Block: 4 waves x 16 q = 64 q.
// ---------------------------------------------------------------------------
__global__ __launch_bounds__(256) void attn3_kernel(const f16* __restrict__ Qh,
                                                    const f16* __restrict__ Kh,
                                                    const f16* __restrict__ Vh,
                                                    const unsigned int* __restrict__ mbits,
                                                    f16* __restrict__ out)
{
    __shared__ f16 Kl[64 * 40];
    __shared__ f16 Vt[32 * 72];      // V^T [d][k], stride 72
    __shared__ f16 Ql[64 * 40];
    __shared__ f16 Pl[4][16 * 72];   // per-wave P: 16 q-rows x 64 keys + pad
    __shared__ unsigned int Ml[64][2];
    const int bh = blockIdx.y, b = bh >> 3, h = bh & 7;
    const int q0 = blockIdx.x * 64;
    const int tid = threadIdx.x, wv = tid >> 6, lane = tid & 63;
    const int g = lane >> 4, fr = lane & 15;
    const size_t kvbase = (size_t)bh * SEQ * DHD;

    {   // stage Q (64x32)
        const int row = tid >> 2, col = (tid & 3) * 8;
        *(f16x8*)&Ql[row * 40 + col] = *(const f16x8*)&Qh[kvbase + (size_t)(q0 + row) * DHD + col];
    }
    const int mrowbase = b * SEQ + q0;
    const float scale = 0.17677669529663687f;
    float mrun = -3.0e38f, lrun = 0.f;
    f32x4 o0 = {0.f, 0.f, 0.f, 0.f}, o1 = {0.f, 0.f, 0.f, 0.f};

    for (int t = 0; t < 16; ++t) {
        __syncthreads();
        {   // stage K tile (64x32)
            const int row = tid >> 2, col = (tid & 3) * 8;
            *(f16x8*)&Kl[row * 40 + col] = *(const f16x8*)&Kh[kvbase + (size_t)(t * 64 + row) * DHD + col];
        }
        {   // stage V^T
            const int k = tid & 63, d0 = (tid >> 6) * 8;
            const f16x8 v = *(const f16x8*)&Vh[kvbase + (size_t)(t * 64 + k) * DHD + d0];
            #pragma unroll
            for (int j = 0; j < 8; ++j) Vt[(d0 + j) * 72 + k] = v[j];
        }
        if (tid < 128) {
            const int i = tid >> 1, w = tid & 1;
            Ml[i][w] = mbits[(size_t)(mrowbase + i) * (SEQ / 32) + t * 2 + w];
        }
        __syncthreads();

        const f16x8 bq = *(const f16x8*)&Ql[(wv * 16 + fr) * 40 + g * 8];
        f32x4 s[4];
        #pragma unroll
        for (int f = 0; f < 4; ++f) {
            const f16x8 ak = *(const f16x8*)&Kl[(f * 16 + fr) * 40 + g * 8];
            const f32x4 z = {0.f, 0.f, 0.f, 0.f};
            s[f] = __builtin_amdgcn_mfma_f32_16x16x32_f16(ak, bq, z, 0, 0, 0);
        }
        const unsigned long long mb =
            ((unsigned long long)Ml[wv * 16 + fr][1] << 32) | (unsigned long long)Ml[wv * 16 + fr][0];
        float tm = -3.0e38f;
        #pragma unroll
        for (int f = 0; f < 4; ++f)
            #pragma unroll
            for (int r = 0; r < 4; ++r) {
                const int kk = f * 16 + g * 4 + r;
                const float v = ((mb >> kk) & 1ULL) ? -1e9f : s[f][r] * scale;
                s[f][r] = v;
                tm = fmaxf(tm, v);
            }
        tm = fmaxf(tm, __shfl_xor(tm, 16, 64));
        tm = fmaxf(tm, __shfl_xor(tm, 32, 64));
        const float mnew = fmaxf(mrun, tm);
        const float resc = __expf(mrun - mnew);
        mrun = mnew;
        lrun *= resc;
        float ps = 0.f;
        #pragma unroll
        for (int f = 0; f < 4; ++f)
            #pragma unroll
            for (int r = 0; r < 4; ++r) {
                const float p = __expf(s[f][r] - mnew);
                s[f][r] = p;
                ps += p;
            }
        ps += __shfl_xor(ps, 16, 64);
        ps += __shfl_xor(ps, 32, 64);
        lrun += ps;
        #pragma unroll
        for (int r = 0; r < 4; ++r) {
            const float rs = __shfl(resc, g * 4 + r, 64);
            o0[r] *= rs;
            o1[r] *= rs;
        }
        #pragma unroll
        for (int f = 0; f < 4; ++f) {
            f16x4 pw = { (f16)s[f][0], (f16)s[f][1], (f16)s[f][2], (f16)s[f][3] };
            *(f16x4*)&Pl[wv][fr * 72 + f * 16 + g * 4] = pw;
        }
        #pragma unroll
        for (int kh = 0; kh < 2; ++kh) {
            const f16x8 pa = *(const f16x8*)&Pl[wv][fr * 72 + kh * 32 + g * 8];
            const f16x8 v0 = *(const f16x8*)&Vt[fr * 72 + kh * 32 + g * 8];
            const f16x8 v1 = *(const f16x8*)&Vt[(16 + fr) * 72 + kh * 32 + g * 8];
            o0 = __builtin_amdgcn_mfma_f32_16x16x32_f16(pa, v0, o0, 0, 0, 0);
            o1 = __builtin_amdgcn_mfma_f32_16x16x32_f16(pa, v1, o1, 0, 0, 0);
        }
    }
    #pragma unroll
    for (int r = 0; r < 4; ++r) {
        const float inv = 1.f / __shfl(lrun, g * 4 + r, 64);
        const int qg = q0 + wv * 16 + g * 4 + r;
        f16* orow = out + ((size_t)(b * SEQ + qg)) * DM + h * DHD;
        orow[fr]      = (f16)(o0[r] * inv);
        orow[16 + fr] = (f16)(o1[r] * inv);
    }
}

// ---------------------------------------------------------------------------
// LN-lite: wave-per-row, no LDS, no barriers. 4 rows/block, grid = ROWS/4.
// x = LayerNorm(x + t)*g + b ; also f16 mirror xh
// ---------------------------------------------------------------------------
__global__ __launch_bounds__(256) void add_ln_kernel(float* __restrict__ x,
                                                     f16* __restrict__ xh,
                                                     const float* __restrict__ t,
                                                     const float* __restrict__ g,
                                                     const float* __restrict__ b)
{
    const int wv = threadIdx.x >> 6, lane = threadIdx.x & 63;
    const int row = blockIdx.x * 4 + wv;
    const size_t base = (size_t)row * DM + lane * 4;
    const float4 xv = *(const float4*)&x[base];
    const float4 tv = *(const float4*)&t[base];
    const float v0 = xv.x + tv.x, v1 = xv.y + tv.y;
    const float v2 = xv.z + tv.z, v3 = xv.w + tv.w;
    float s = v0 + v1 + v2 + v3;
    #pragma unroll
    for (int o = 32; o; o >>= 1) s += __shfl_xor(s, o, 64);
    const float mean = s * (1.f / DM);
    const float d0 = v0 - mean, d1 = v1 - mean, d2 = v2 - mean, d3 = v3 - mean;
    float q = d0 * d0 + d1 * d1 + d2 * d2 + d3 * d3;
    #pragma unroll
    for (int o = 32; o; o >>= 1) q += __shfl_xor(q, o, 64);
    const float rs = rsqrtf(q * (1.f / DM) + 1e-5f);
    const float4 gv = *(const float4*)&g[lane * 4];
    const float4 bv = *(const float4*)&b[lane * 4];
    float4 ov;
    ov.x = d0 * rs * gv.x + bv.x;
    ov.y = d1 * rs * gv.y + bv.y;
    ov.z = d2 * rs * gv.z + bv.z;
    ov.w = d3 * rs * gv.w + bv.w;
    *(float4*)&x[base] = ov;
    f16x4 hv = { (f16)ov.x, (f16)ov.y, (f16)ov.z, (f16)ov.w };
    *(f16x4*)&xh[base] = hv;
}

// ---------------------------------------------------------------------------
// decoder (f32)
// ---------------------------------------------------------------------------
__global__ __launch_bounds__(256) void dec_kernel(const float* __restrict__ x,
                                                  const float* __restrict__ w,
                                                  const float* __restrict__ bias,
                                                  float* __restrict__ out)
{
    const int idx = blockIdx.x * 256 + threadIdx.x;
    if (idx >= BATCH * SEQ * OUTD) return;
    const int row = idx / OUTD, o = idx % OUTD;
    const float* xr = x + (size_t)row * DM;
    const float* wr = w + o * DM;
    float s = bias[o];
    for (int d = 0; d < DM; ++d) s += xr[d] * wr[d];
    out[idx] = s;
}

// ---------------------------------------------------------------------------
extern "C" void kernel_launch(void* const* d_in, const int* in_sizes, int n_in,
                              void* d_out, int out_size, void* d_ws, size_t ws_size,
                              hipStream_t stream)
{
    (void)in_sizes; (void)n_in; (void)out_size; (void)ws_size;
    const float* in_coord = (const float*)d_in[0];
    const float* in_maskf = (const float*)d_in[1];
    const void*  praw     = d_in[2];
    const float* w_in  = (const float*)d_in[3];
    const float* b_in  = (const float*)d_in[4];
    const float* w_qkv = (const float*)d_in[5];
    const float* b_qkv = (const float*)d_in[6];
    const float* w_o   = (const float*)d_in[7];
    const float* b_o   = (const float*)d_in[8];
    const float* w_ff1 = (const float*)d_in[9];
    const float* b_ff1 = (const float*)d_in[10];
    const float* w_ff2 = (const float*)d_in[11];
    const float* b_ff2 = (const float*)d_in[12];
    const float* ln1_g = (const float*)d_in[13];
    const float* ln1_b = (const float*)d_in[14];
    const float* ln2_g = (const float*)d_in[15];
    const float* ln2_b = (const float*)d_in[16];
    const float* w_dec = (const float*)d_in[17];
    const float* b_dec = (const float*)d_in[18];

    const int ROWS = BATCH * SEQ;                 // 4096
    float* x   = (float*)d_ws;                    // 1M f32
    float* tmp = x + 1048576;                     // 1M f32
    f16* us = (f16*)(tmp + 1048576);
    f16* xh    = us;  us += 1048576;
    f16* qkvb  = us;  us += 3145728;
    f16* Qh    = us;  us += 1048576;
    f16* Kh    = us;  us += 1048576;
    f16* Vh    = us;  us += 1048576;
    f16* attno = us;  us += 1048576;
    f16* hb    = us;  us += 4194304;
    f16* wqb   = us;  us += 786432;
    f16* wob   = us;  us += 262144;
    f16* w1b   = us;  us += 1048576;
    f16* w2b   = us;  us += 1048576;
    unsigned int*  mbits  = (unsigned int*)us;    // 131072 u32
    unsigned char* padb   = (unsigned char*)(mbits + 131072);

    hipLaunchKernelGGL(pad_kernel, dim3(1), dim3(1024), 0, stream, praw, padb);
    hipLaunchKernelGGL(mask_kernel, dim3(BATCH * SEQ), dim3(256), 0, stream,
                       in_maskf, padb, mbits);
    hipLaunchKernelGGL(embed_kernel, dim3(ROWS), dim3(256), 0, stream,
                       in_coord, w_in, b_in, x, xh);
    hipLaunchKernelGGL(castw4_kernel, dim3(1536), dim3(256), 0, stream,
                       w_qkv, wqb, 786432,
                       w_o,   wob, 262144,
                       w_ff1, w1b, 1048576,
                       w_ff2, w2b, 1048576);

    for (int l = 0; l < NL; ++l) {
        hipLaunchKernelGGL((mgemm_kernel<128>), dim3(768 / 128, ROWS / 128), dim3(256), 0, stream,
                           xh, wqb + (size_t)l * 196608, b_qkv + l * 768, (void*)qkvb,
                           ROWS, 768, 256, 0, 1);
        hipLaunchKernelGGL(split_heads_kernel, dim3(ROWS), dim3(256), 0, stream,
                           qkvb, Qh, Kh, Vh);
        hipLaunchKernelGGL(attn3_kernel, dim3(SEQ / 64, BATCH * NH), dim3(256), 0, stream,
                           Qh, Kh, Vh, mbits, attno);
        hipLaunchKernelGGL((mgemm_kernel<64>), dim3(256 / 64, ROWS / 64), dim3(256), 0, stream,
                           attno, wob + (size_t)l * 65536, b_o + l * 256, (void*)tmp,
                           ROWS, 256, 256, 0, 0);
        hipLaunchKernelGGL(add_ln_kernel, dim3(ROWS / 4), dim3(256), 0, stream,
                           x, xh, tmp, ln1_g + l * DM, ln1_b + l * DM);
        hipLaunchKernelGGL((mgemm_kernel<128>), dim3(1024 / 128, ROWS / 128), dim3(256), 0, stream,
                           xh, w1b + (size_t)l * 262144, b_ff1 + l * 1024, (void*)hb,
                           ROWS, 1024, 256, 1, 1);
        hipLaunchKernelGGL((mgemm_kernel<64>), dim3(256 / 64, ROWS / 64), dim3(256), 0, stream,
                           hb, w2b + (size_t)l * 262144, b_ff2 + l * 256, (void*)tmp,
                           ROWS, 256, 1024, 0, 0);
        hipLaunchKernelGGL(add_ln_kernel, dim3(ROWS / 4), dim3(256), 0, stream,
                           x, xh, tmp, ln2_g + l * DM, ln2_b + l * DM);
    }

    hipLaunchKernelGGL(dec_kernel, dim3((ROWS * OUTD + 255) / 256), dim3(256), 0, stream,
                       x, w_dec, b_dec, (float*)d_out);
}